// Round 3
// baseline (351.657 us; speedup 1.0000x reference)
//
#include <hip/hip_runtime.h>
#include <math.h>

#define IN_DIM 256
#define HID 64
#define OUT_DIM 40
#define EPS_RES 0.3f
#define SCAN_BLK 256

__device__ __forceinline__ float tanh_fast(float u) {
    // tanh(u) = 1 - 2/(exp(2u)+1); exact limits at +-inf
    float t = __expf(2.0f * u);
    return 1.0f - 2.0f / (t + 1.0f);
}

// ---------------------------------------------------------------- degree
__global__ void k_deg(const int* __restrict__ dst, int* __restrict__ deg, int E) {
    int i = blockIdx.x * blockDim.x + threadIdx.x;
    if (i < E) atomicAdd(&deg[dst[i]], 1);
}

__global__ void k_dinv(const int* __restrict__ deg, float* __restrict__ dinv, int N) {
    int i = blockIdx.x * blockDim.x + threadIdx.x;
    if (i < N) dinv[i] = rsqrtf(fmaxf((float)deg[i], 1.0f));
}

// ------------------------------------------------------- CSR build: scan
__global__ void k_scan_block(const int* __restrict__ deg, int* __restrict__ incl,
                             int* __restrict__ bsum, int N) {
    __shared__ int sm[SCAN_BLK];
    int tid = threadIdx.x;
    int i = blockIdx.x * SCAN_BLK + tid;
    sm[tid] = (i < N) ? deg[i] : 0;
    __syncthreads();
    for (int off = 1; off < SCAN_BLK; off <<= 1) {
        int t = (tid >= off) ? sm[tid - off] : 0;
        __syncthreads();
        sm[tid] += t;
        __syncthreads();
    }
    if (i < N) incl[i] = sm[tid];
    if (tid == SCAN_BLK - 1) bsum[blockIdx.x] = sm[tid];
}

// NB <= 256
__global__ void k_scan_tops(const int* __restrict__ bsum, int* __restrict__ boff, int NB) {
    __shared__ int sm[SCAN_BLK];
    int tid = threadIdx.x;
    int v = (tid < NB) ? bsum[tid] : 0;
    sm[tid] = v;
    __syncthreads();
    for (int off = 1; off < SCAN_BLK; off <<= 1) {
        int t = (tid >= off) ? sm[tid - off] : 0;
        __syncthreads();
        sm[tid] += t;
        __syncthreads();
    }
    if (tid < NB) boff[tid] = sm[tid] - v;  // exclusive block offsets
}

__global__ void k_scan_add(const int* __restrict__ incl, const int* __restrict__ boff,
                           const int* __restrict__ deg, int* __restrict__ rowp,
                           int* __restrict__ cursor, int N) {
    int i = blockIdx.x * SCAN_BLK + threadIdx.x;
    if (i >= N) return;
    int inc = incl[i] + boff[blockIdx.x];
    rowp[i + 1] = inc;
    cursor[i] = inc - deg[i];
    if (i == 0) rowp[0] = 0;
}

__global__ void k_place(const int* __restrict__ src, const int* __restrict__ dst,
                        int* __restrict__ cursor, int* __restrict__ ssrc, int E) {
    int i = blockIdx.x * blockDim.x + threadIdx.x;
    if (i >= E) return;
    int t = dst[i];
    int p = atomicAdd(&cursor[t], 1);
    ssrc[p] = src[i];
}

// --------------------- x0 = relu(h @ W1^T + b1), fused gate proj for layer 1
// LDS-staged h tile (64 rows x 256 cols, XOR-swizzled float4 slots).
// Stage: wave reads one full 1KB row per instr group (coalesced); swizzle
// slot = c ^ (r&7) makes every 8-lane compute read cover one 128B line
// conflict-free. Compute: lane=row, wave=16-col slice, W/bias scalar loads.
__global__ __launch_bounds__(256) void k_gemm1(
    const float* __restrict__ h, const float* __restrict__ w,
    const float* __restrict__ b, const float* __restrict__ gw,
    float* __restrict__ out, float* __restrict__ gpa, float* __restrict__ gpb,
    int N) {
    __shared__ float4 tile[64 * 64];     // 64KB
    __shared__ float red[2][4][64];      // cross-wave gate-proj reduce

    int tid = threadIdx.x;
    int row0 = blockIdx.x * 64;

    // ---- stage (coalesced global -> swizzled LDS)
#pragma unroll
    for (int i = 0; i < 16; ++i) {
        int g = i * 256 + tid;           // 0..4095 slot id
        int r = g >> 6;                  // row in tile
        int cs = g & 63;                 // swizzled slot
        int c = cs ^ (r & 7);            // source float4 col
        int row = row0 + r;
        if (row >= N) row = N - 1;
        tile[g] = *(const float4*)(h + (size_t)row * IN_DIM + c * 4);
    }
    __syncthreads();

    int lane = tid & 63;
    int wv = __builtin_amdgcn_readfirstlane(tid >> 6);
    int c0 = wv * 16;
    int row = row0 + lane;

    float acc[16];
#pragma unroll
    for (int j = 0; j < 16; ++j) acc[j] = b[c0 + j];

#pragma unroll 2
    for (int kb = 0; kb < 64; ++kb) {
        float4 hv = tile[(lane << 6) | (kb ^ (lane & 7))];
        const float* wr = w + (size_t)c0 * IN_DIM + kb * 4;
#pragma unroll
        for (int j = 0; j < 16; ++j) {
            acc[j] = fmaf(hv.x, wr[j * IN_DIM + 0], acc[j]);
            acc[j] = fmaf(hv.y, wr[j * IN_DIM + 1], acc[j]);
            acc[j] = fmaf(hv.z, wr[j * IN_DIM + 2], acc[j]);
            acc[j] = fmaf(hv.w, wr[j * IN_DIM + 3], acc[j]);
        }
    }

    // relu + per-wave gate-proj partials
    float pa = 0.f, pb = 0.f;
#pragma unroll
    for (int j = 0; j < 16; ++j) {
        acc[j] = fmaxf(acc[j], 0.f);
        pa = fmaf(acc[j], gw[c0 + j], pa);
        pb = fmaf(acc[j], gw[HID + c0 + j], pb);
    }
    red[0][wv][lane] = pa;
    red[1][wv][lane] = pb;

    if (row < N) {
        float4* o = (float4*)(out + (size_t)row * HID + c0);
#pragma unroll
        for (int q = 0; q < 4; ++q)
            o[q] = make_float4(acc[q * 4 + 0], acc[q * 4 + 1],
                               acc[q * 4 + 2], acc[q * 4 + 3]);
    }
    __syncthreads();
    if (tid < 128) {
        int which = tid >> 6;            // 0 -> gpa, 1 -> gpb
        float s = red[which][0][lane] + red[which][1][lane]
                + red[which][2][lane] + red[which][3][lane];
        if (row0 + lane < N) (which ? gpb : gpa)[row0 + lane] = s;
    }
}

// ---- gather: z[t] = EPS*raw[t] + sum_e tanh(ga[t]+gb[s]+bias)*d[t]*d[s]*x[s]
// one wave per node, lane = hid dim; edge gate computed inline (scalar loads,
// wave-redundant VALU hidden under x-row gather latency). Epilogue computes
// next layer's gate projections via wave shfl reduce.
__global__ __launch_bounds__(256) void k_gather(
    const int* __restrict__ rowp, const int* __restrict__ ssrc,
    const float* __restrict__ gpa, const float* __restrict__ gpb,
    const float* __restrict__ dinv, const float* __restrict__ gbias,
    const float* __restrict__ x, const float* __restrict__ raw,
    float* __restrict__ z,
    const float* __restrict__ gw_next, float* __restrict__ gpa_next,
    float* __restrict__ gpb_next, int N) {
    int lane = threadIdx.x & 63;
    int wv = __builtin_amdgcn_readfirstlane(threadIdx.x >> 6);
    int t = blockIdx.x * 4 + wv;
    if (t >= N) return;

    float at = gpa[t] + gbias[0];
    float dt = dinv[t];
    float acc = EPS_RES * raw[((size_t)t << 6) + lane];
    int k = rowp[t];
    int end = rowp[t + 1];
    for (; k + 2 <= end; k += 2) {
        int s0 = ssrc[k], s1 = ssrc[k + 1];
        float e0 = tanh_fast(at + gpb[s0]) * dt * dinv[s0];
        float e1 = tanh_fast(at + gpb[s1]) * dt * dinv[s1];
        acc = fmaf(e0, x[((size_t)s0 << 6) + lane], acc);
        acc = fmaf(e1, x[((size_t)s1 << 6) + lane], acc);
    }
    if (k < end) {
        int s0 = ssrc[k];
        float e0 = tanh_fast(at + gpb[s0]) * dt * dinv[s0];
        acc = fmaf(e0, x[((size_t)s0 << 6) + lane], acc);
    }
    z[((size_t)t << 6) + lane] = acc;

    if (gw_next) {
        float pa = acc * gw_next[lane];
        float pb = acc * gw_next[HID + lane];
#pragma unroll
        for (int m = 32; m; m >>= 1) {
            pa += __shfl_xor(pa, m);
            pb += __shfl_xor(pb, m);
        }
        if (lane == 0) {
            gpa_next[t] = pa;
            gpb_next[t] = pb;
        }
    }
}

// ------------------------------------- logits = x @ W2^T + b2, log_softmax
__global__ __launch_bounds__(256) void k_head(
    const float* __restrict__ x, const float* __restrict__ w2,
    const float* __restrict__ b2, float* __restrict__ out, int N) {
    int n = blockIdx.x * 256 + threadIdx.x;
    if (n >= N) return;
    const float4* xr = (const float4*)(x + (size_t)n * HID);
    float acc[OUT_DIM];
#pragma unroll
    for (int j = 0; j < OUT_DIM; ++j) acc[j] = b2[j];
#pragma unroll 2
    for (int kb = 0; kb < HID / 4; ++kb) {
        float4 v = xr[kb];
#pragma unroll
        for (int j = 0; j < OUT_DIM; ++j) {
            const float* wr = w2 + (size_t)j * HID + kb * 4;
            acc[j] = fmaf(v.x, wr[0], acc[j]);
            acc[j] = fmaf(v.y, wr[1], acc[j]);
            acc[j] = fmaf(v.z, wr[2], acc[j]);
            acc[j] = fmaf(v.w, wr[3], acc[j]);
        }
    }
    float m = acc[0];
#pragma unroll
    for (int j = 1; j < OUT_DIM; ++j) m = fmaxf(m, acc[j]);
    float ssum = 0.f;
#pragma unroll
    for (int j = 0; j < OUT_DIM; ++j) ssum += expf(acc[j] - m);
    float lse = m + logf(ssum);
    float* o = out + (size_t)n * OUT_DIM;
#pragma unroll
    for (int j = 0; j < OUT_DIM; ++j) o[j] = acc[j] - lse;
}

// ----------------------------------------------------------------- launcher
extern "C" void kernel_launch(void* const* d_in, const int* in_sizes, int n_in,
                              void* d_out, int out_size, void* d_ws, size_t ws_size,
                              hipStream_t stream) {
    const float* h    = (const float*)d_in[0];
    const int*   src  = (const int*)d_in[1];
    const int*   dst  = (const int*)d_in[2];
    const float* t1_w = (const float*)d_in[3];
    const float* t1_b = (const float*)d_in[4];
    const float* gw1  = (const float*)d_in[5];
    const float* gb1  = (const float*)d_in[6];
    const float* gw2  = (const float*)d_in[7];
    const float* gb2  = (const float*)d_in[8];
    const float* t2_w = (const float*)d_in[9];
    const float* t2_b = (const float*)d_in[10];
    float* out = (float*)d_out;

    const int N = in_sizes[0] / IN_DIM;
    const int E = in_sizes[1];
    const int NB = (N + SCAN_BLK - 1) / SCAN_BLK;

    // workspace layout
    float* ws   = (float*)d_ws;
    float* raw  = ws;                          // N*64
    float* xA   = raw + (size_t)N * HID;       // N*64
    float* xB   = xA + (size_t)N * HID;        // N*64
    float* dinv = xB + (size_t)N * HID;        // N
    float* gpa1 = dinv + N;                    // N
    float* gpb1 = gpa1 + N;                    // N
    float* gpa2 = gpb1 + N;                    // N
    float* gpb2 = gpa2 + N;                    // N
    int* deg    = (int*)(gpb2 + N);            // N
    int* incl   = deg + N;                     // N
    int* rowp   = incl + N;                    // N+1
    int* cursor = rowp + N + 1;                // N
    int* bsum   = cursor + N;                  // NB
    int* boff   = bsum + NB;                   // NB
    int* ssrc   = boff + NB;                   // E

    const int TB = 256;
    hipMemsetAsync(deg, 0, (size_t)N * sizeof(int), stream);
    k_deg<<<(E + TB - 1) / TB, TB, 0, stream>>>(dst, deg, E);
    k_dinv<<<NB, TB, 0, stream>>>(deg, dinv, N);
    k_scan_block<<<NB, TB, 0, stream>>>(deg, incl, bsum, N);
    k_scan_tops<<<1, TB, 0, stream>>>(bsum, boff, NB);
    k_scan_add<<<NB, TB, 0, stream>>>(incl, boff, deg, rowp, cursor, N);
    k_place<<<(E + TB - 1) / TB, TB, 0, stream>>>(src, dst, cursor, ssrc, E);

    // x0 = relu(h W1^T + b1), plus layer-1 gate projections
    k_gemm1<<<(N + 63) / 64, TB, 0, stream>>>(h, t1_w, t1_b, gw1, raw, gpa1, gpb1, N);

    // layer 1: raw -> xA (epilogue computes layer-2 gate projections)
    k_gather<<<(N + 3) / 4, TB, 0, stream>>>(rowp, ssrc, gpa1, gpb1, dinv, gb1,
                                             raw, raw, xA, gw2, gpa2, gpb2, N);

    // layer 2: xA -> xB
    k_gather<<<(N + 3) / 4, TB, 0, stream>>>(rowp, ssrc, gpa2, gpb2, dinv, gb2,
                                             xA, raw, xB, nullptr, nullptr, nullptr, N);

    k_head<<<(N + TB - 1) / TB, TB, 0, stream>>>(xB, t2_w, t2_b, out, N);
}

// Round 4
// 344.532 us; speedup vs baseline: 1.0207x; 1.0207x over previous
//
#include <hip/hip_runtime.h>
#include <math.h>

#define IN_DIM 256
#define HID 64
#define OUT_DIM 40
#define EPS_RES 0.3f
#define SCAN_BLK 256

__device__ __forceinline__ float tanh_fast(float u) {
    // tanh(u) = 1 - 2/(exp(2u)+1); exact limits at +-inf
    float t = __expf(2.0f * u);
    return 1.0f - 2.0f / (t + 1.0f);
}

// ---------------------------------------------------------------- degree
__global__ void k_deg(const int* __restrict__ dst, int* __restrict__ deg, int E) {
    int i = blockIdx.x * blockDim.x + threadIdx.x;
    if (i < E) atomicAdd(&deg[dst[i]], 1);
}

__global__ void k_dinv(const int* __restrict__ deg, float* __restrict__ dinv, int N) {
    int i = blockIdx.x * blockDim.x + threadIdx.x;
    if (i < N) dinv[i] = rsqrtf(fmaxf((float)deg[i], 1.0f));
}

// ------------------------------------------------------- CSR build: scan
__global__ void k_scan_block(const int* __restrict__ deg, int* __restrict__ incl,
                             int* __restrict__ bsum, int N) {
    __shared__ int sm[SCAN_BLK];
    int tid = threadIdx.x;
    int i = blockIdx.x * SCAN_BLK + tid;
    sm[tid] = (i < N) ? deg[i] : 0;
    __syncthreads();
    for (int off = 1; off < SCAN_BLK; off <<= 1) {
        int t = (tid >= off) ? sm[tid - off] : 0;
        __syncthreads();
        sm[tid] += t;
        __syncthreads();
    }
    if (i < N) incl[i] = sm[tid];
    if (tid == SCAN_BLK - 1) bsum[blockIdx.x] = sm[tid];
}

// NB <= 256
__global__ void k_scan_tops(const int* __restrict__ bsum, int* __restrict__ boff, int NB) {
    __shared__ int sm[SCAN_BLK];
    int tid = threadIdx.x;
    int v = (tid < NB) ? bsum[tid] : 0;
    sm[tid] = v;
    __syncthreads();
    for (int off = 1; off < SCAN_BLK; off <<= 1) {
        int t = (tid >= off) ? sm[tid - off] : 0;
        __syncthreads();
        sm[tid] += t;
        __syncthreads();
    }
    if (tid < NB) boff[tid] = sm[tid] - v;  // exclusive block offsets
}

__global__ void k_scan_add(const int* __restrict__ incl, const int* __restrict__ boff,
                           const int* __restrict__ deg, int* __restrict__ rowp,
                           int* __restrict__ cursor, int N) {
    int i = blockIdx.x * SCAN_BLK + threadIdx.x;
    if (i >= N) return;
    int inc = incl[i] + boff[blockIdx.x];
    rowp[i + 1] = inc;
    cursor[i] = inc - deg[i];
    if (i == 0) rowp[0] = 0;
}

__global__ void k_place(const int* __restrict__ src, const int* __restrict__ dst,
                        int* __restrict__ cursor, int* __restrict__ ssrc, int E) {
    int i = blockIdx.x * blockDim.x + threadIdx.x;
    if (i >= E) return;
    int t = dst[i];
    int p = atomicAdd(&cursor[t], 1);
    ssrc[p] = src[i];
}

// --------------------- x0 = relu(h @ W1^T + b1), fused gate proj for layer 1
// k-split LDS staging: two 64x128 f32 half-tiles (32KB + 2KB -> 4 blocks/CU).
// Stage coalesced (wave = 2 rows x 512B); XOR-swizzled float4 slots so the
// compute column-read (64 lanes, same kb) is conflict-free. Half-1 global
// loads are issued into registers BEFORE half-0 compute (latency hidden
// under 2048 FMAs). Compute: lane=row, wave=16-col slice, W scalar loads.
__global__ __launch_bounds__(256) void k_gemm1(
    const float* __restrict__ h, const float* __restrict__ w,
    const float* __restrict__ b, const float* __restrict__ gw,
    float* __restrict__ out, float* __restrict__ gpa, float* __restrict__ gpb,
    int N) {
    __shared__ float4 tile[64 * 32];     // 32KB: 64 rows x 32 swizzled float4
    __shared__ float red[2][4][64];      // cross-wave gate-proj reduce (2KB)

    int tid = threadIdx.x;
    int row0 = blockIdx.x * 64;
    int lane = tid & 63;
    int wv = __builtin_amdgcn_readfirstlane(tid >> 6);
    int c0 = wv * 16;
    int row = row0 + lane;

    const float4* hf4 = (const float4*)h;   // 64 float4 per source row

    float4 pre[8];
    // ---- load half 0 (cols 0..31 of float4 row) — coalesced
#pragma unroll
    for (int i = 0; i < 8; ++i) {
        int s = i * 256 + tid;
        int r = s >> 5, c = s & 31;
        int rr = row0 + r; if (rr >= N) rr = N - 1;
        pre[i] = hf4[(size_t)rr * 64 + c];
    }
#pragma unroll
    for (int i = 0; i < 8; ++i) {
        int s = i * 256 + tid;
        int r = s >> 5, c = s & 31;
        tile[(r << 5) | (c ^ (r & 7))] = pre[i];
    }
    __syncthreads();

    // ---- issue half-1 loads (in flight under half-0 compute)
#pragma unroll
    for (int i = 0; i < 8; ++i) {
        int s = i * 256 + tid;
        int r = s >> 5, c = s & 31;
        int rr = row0 + r; if (rr >= N) rr = N - 1;
        pre[i] = hf4[(size_t)rr * 64 + 32 + c];
    }

    float acc[16];
#pragma unroll
    for (int j = 0; j < 16; ++j) acc[j] = b[c0 + j];

    // ---- compute half 0
#pragma unroll 4
    for (int kb = 0; kb < 32; ++kb) {
        float4 hv = tile[(lane << 5) | (kb ^ (lane & 7))];
        const float* wr = w + (size_t)c0 * IN_DIM + kb * 4;
#pragma unroll
        for (int j = 0; j < 16; ++j) {
            acc[j] = fmaf(hv.x, wr[j * IN_DIM + 0], acc[j]);
            acc[j] = fmaf(hv.y, wr[j * IN_DIM + 1], acc[j]);
            acc[j] = fmaf(hv.z, wr[j * IN_DIM + 2], acc[j]);
            acc[j] = fmaf(hv.w, wr[j * IN_DIM + 3], acc[j]);
        }
    }
    __syncthreads();

    // ---- write half 1
#pragma unroll
    for (int i = 0; i < 8; ++i) {
        int s = i * 256 + tid;
        int r = s >> 5, c = s & 31;
        tile[(r << 5) | (c ^ (r & 7))] = pre[i];
    }
    __syncthreads();

    // ---- compute half 1
#pragma unroll 4
    for (int kb = 0; kb < 32; ++kb) {
        float4 hv = tile[(lane << 5) | (kb ^ (lane & 7))];
        const float* wr = w + (size_t)c0 * IN_DIM + 128 + kb * 4;
#pragma unroll
        for (int j = 0; j < 16; ++j) {
            acc[j] = fmaf(hv.x, wr[j * IN_DIM + 0], acc[j]);
            acc[j] = fmaf(hv.y, wr[j * IN_DIM + 1], acc[j]);
            acc[j] = fmaf(hv.z, wr[j * IN_DIM + 2], acc[j]);
            acc[j] = fmaf(hv.w, wr[j * IN_DIM + 3], acc[j]);
        }
    }

    // relu + per-wave gate-proj partials
    float pa = 0.f, pb = 0.f;
#pragma unroll
    for (int j = 0; j < 16; ++j) {
        acc[j] = fmaxf(acc[j], 0.f);
        pa = fmaf(acc[j], gw[c0 + j], pa);
        pb = fmaf(acc[j], gw[HID + c0 + j], pb);
    }
    red[0][wv][lane] = pa;
    red[1][wv][lane] = pb;

    if (row < N) {
        float4* o = (float4*)(out + (size_t)row * HID + c0);
#pragma unroll
        for (int q = 0; q < 4; ++q)
            o[q] = make_float4(acc[q * 4 + 0], acc[q * 4 + 1],
                               acc[q * 4 + 2], acc[q * 4 + 3]);
    }
    __syncthreads();
    if (tid < 128) {
        int which = tid >> 6;            // 0 -> gpa, 1 -> gpb
        float s = red[which][0][lane] + red[which][1][lane]
                + red[which][2][lane] + red[which][3][lane];
        if (row0 + lane < N) (which ? gpb : gpa)[row0 + lane] = s;
    }
}

// ---- gather: z[t] = EPS*raw[t] + sum_e tanh(ga[t]+gb[s]+bias)*d[t]*d[s]*x[s]
// one wave per node, lane = hid dim; edge gate computed inline (scalar loads,
// wave-redundant VALU hidden under x-row gather latency). Epilogue computes
// next layer's gate projections via wave shfl reduce.
__global__ __launch_bounds__(256) void k_gather(
    const int* __restrict__ rowp, const int* __restrict__ ssrc,
    const float* __restrict__ gpa, const float* __restrict__ gpb,
    const float* __restrict__ dinv, const float* __restrict__ gbias,
    const float* __restrict__ x, const float* __restrict__ raw,
    float* __restrict__ z,
    const float* __restrict__ gw_next, float* __restrict__ gpa_next,
    float* __restrict__ gpb_next, int N) {
    int lane = threadIdx.x & 63;
    int wv = __builtin_amdgcn_readfirstlane(threadIdx.x >> 6);
    int t = blockIdx.x * 4 + wv;
    if (t >= N) return;

    float at = gpa[t] + gbias[0];
    float dt = dinv[t];
    float acc = EPS_RES * raw[((size_t)t << 6) + lane];
    int k = rowp[t];
    int end = rowp[t + 1];
    for (; k + 2 <= end; k += 2) {
        int s0 = ssrc[k], s1 = ssrc[k + 1];
        float e0 = tanh_fast(at + gpb[s0]) * dt * dinv[s0];
        float e1 = tanh_fast(at + gpb[s1]) * dt * dinv[s1];
        acc = fmaf(e0, x[((size_t)s0 << 6) + lane], acc);
        acc = fmaf(e1, x[((size_t)s1 << 6) + lane], acc);
    }
    if (k < end) {
        int s0 = ssrc[k];
        float e0 = tanh_fast(at + gpb[s0]) * dt * dinv[s0];
        acc = fmaf(e0, x[((size_t)s0 << 6) + lane], acc);
    }
    z[((size_t)t << 6) + lane] = acc;

    if (gw_next) {
        float pa = acc * gw_next[lane];
        float pb = acc * gw_next[HID + lane];
#pragma unroll
        for (int m = 32; m; m >>= 1) {
            pa += __shfl_xor(pa, m);
            pb += __shfl_xor(pb, m);
        }
        if (lane == 0) {
            gpa_next[t] = pa;
            gpb_next[t] = pb;
        }
    }
}

// ------------------------------------- logits = x @ W2^T + b2, log_softmax
__global__ __launch_bounds__(256) void k_head(
    const float* __restrict__ x, const float* __restrict__ w2,
    const float* __restrict__ b2, float* __restrict__ out, int N) {
    int n = blockIdx.x * 256 + threadIdx.x;
    if (n >= N) return;
    const float4* xr = (const float4*)(x + (size_t)n * HID);
    float acc[OUT_DIM];
#pragma unroll
    for (int j = 0; j < OUT_DIM; ++j) acc[j] = b2[j];
#pragma unroll 2
    for (int kb = 0; kb < HID / 4; ++kb) {
        float4 v = xr[kb];
#pragma unroll
        for (int j = 0; j < OUT_DIM; ++j) {
            const float* wr = w2 + (size_t)j * HID + kb * 4;
            acc[j] = fmaf(v.x, wr[0], acc[j]);
            acc[j] = fmaf(v.y, wr[1], acc[j]);
            acc[j] = fmaf(v.z, wr[2], acc[j]);
            acc[j] = fmaf(v.w, wr[3], acc[j]);
        }
    }
    float m = acc[0];
#pragma unroll
    for (int j = 1; j < OUT_DIM; ++j) m = fmaxf(m, acc[j]);
    float ssum = 0.f;
#pragma unroll
    for (int j = 0; j < OUT_DIM; ++j) ssum += expf(acc[j] - m);
    float lse = m + logf(ssum);
    float* o = out + (size_t)n * OUT_DIM;
#pragma unroll
    for (int j = 0; j < OUT_DIM; ++j) o[j] = acc[j] - lse;
}

// ----------------------------------------------------------------- launcher
extern "C" void kernel_launch(void* const* d_in, const int* in_sizes, int n_in,
                              void* d_out, int out_size, void* d_ws, size_t ws_size,
                              hipStream_t stream) {
    const float* h    = (const float*)d_in[0];
    const int*   src  = (const int*)d_in[1];
    const int*   dst  = (const int*)d_in[2];
    const float* t1_w = (const float*)d_in[3];
    const float* t1_b = (const float*)d_in[4];
    const float* gw1  = (const float*)d_in[5];
    const float* gb1  = (const float*)d_in[6];
    const float* gw2  = (const float*)d_in[7];
    const float* gb2  = (const float*)d_in[8];
    const float* t2_w = (const float*)d_in[9];
    const float* t2_b = (const float*)d_in[10];
    float* out = (float*)d_out;

    const int N = in_sizes[0] / IN_DIM;
    const int E = in_sizes[1];
    const int NB = (N + SCAN_BLK - 1) / SCAN_BLK;

    // workspace layout
    float* ws   = (float*)d_ws;
    float* raw  = ws;                          // N*64
    float* xA   = raw + (size_t)N * HID;       // N*64
    float* xB   = xA + (size_t)N * HID;        // N*64
    float* dinv = xB + (size_t)N * HID;        // N
    float* gpa1 = dinv + N;                    // N
    float* gpb1 = gpa1 + N;                    // N
    float* gpa2 = gpb1 + N;                    // N
    float* gpb2 = gpa2 + N;                    // N
    int* deg    = (int*)(gpb2 + N);            // N
    int* incl   = deg + N;                     // N
    int* rowp   = incl + N;                    // N+1
    int* cursor = rowp + N + 1;                // N
    int* bsum   = cursor + N;                  // NB
    int* boff   = bsum + NB;                   // NB
    int* ssrc   = boff + NB;                   // E

    const int TB = 256;
    hipMemsetAsync(deg, 0, (size_t)N * sizeof(int), stream);
    k_deg<<<(E + TB - 1) / TB, TB, 0, stream>>>(dst, deg, E);
    k_dinv<<<NB, TB, 0, stream>>>(deg, dinv, N);
    k_scan_block<<<NB, TB, 0, stream>>>(deg, incl, bsum, N);
    k_scan_tops<<<1, TB, 0, stream>>>(bsum, boff, NB);
    k_scan_add<<<NB, TB, 0, stream>>>(incl, boff, deg, rowp, cursor, N);
    k_place<<<(E + TB - 1) / TB, TB, 0, stream>>>(src, dst, cursor, ssrc, E);

    // x0 = relu(h W1^T + b1), plus layer-1 gate projections
    k_gemm1<<<(N + 63) / 64, TB, 0, stream>>>(h, t1_w, t1_b, gw1, raw, gpa1, gpb1, N);

    // layer 1: raw -> xA (epilogue computes layer-2 gate projections)
    k_gather<<<(N + 3) / 4, TB, 0, stream>>>(rowp, ssrc, gpa1, gpb1, dinv, gb1,
                                             raw, raw, xA, gw2, gpa2, gpb2, N);

    // layer 2: xA -> xB
    k_gather<<<(N + 3) / 4, TB, 0, stream>>>(rowp, ssrc, gpa2, gpb2, dinv, gb2,
                                             xA, raw, xB, nullptr, nullptr, nullptr, N);

    k_head<<<(N + TB - 1) / TB, TB, 0, stream>>>(xB, t2_w, t2_b, out, N);
}